// Round 13
// baseline (116.892 us; speedup 1.0000x reference)
//
#include <hip/hip_runtime.h>

#define NC 1024
#define DY 16
#define NG 65536

#define SZ_WYA (16 * 32 * 64 * 8)  // h16 per m: [jt][ks][lane][jj] A-frag order
#define SZ_YTB (32 * 64 * 8)       // h16 per m: [ks][lane][jj]     B-frag order

typedef float v4f __attribute__((ext_vector_type(4)));
typedef _Float16 h8 __attribute__((ext_vector_type(8)));

// ---- K1: table builder (R9-identical work, repeated `rep` times so it
// surfaces in rocprof top-5 with counters; stores are idempotent). ----
__global__ __launch_bounds__(256) void setconv_tables(
    const float* __restrict__ xc, const float* __restrict__ yc,
    const float* __restrict__ lsp,
    _Float16* __restrict__ WYA, _Float16* __restrict__ YTB, int m, int rep)
{
    const int t  = blockIdx.x * 256 + threadIdx.x;
    const int T1 = m * (SZ_WYA / 8);
    const int T2 = T1 + m * (SZ_YTB / 8);
    if (t >= T2) return;

    for (int r = 0; r < rep; ++r) {
        if (t < T1) {
            const float l1 = 1e-5f + __logf(1.0f + __expf(lsp[1]));
            const float s1 = 0.84932184f / l1;          // sqrt(log2e/2)/l
            const int mm   = t >> 15;
            const int rem  = t & 32767;
            const int jt   = rem >> 11;
            const int ks   = (rem >> 6) & 31;
            const int lane = rem & 63;
            const int j    = jt * 16 + (lane & 15);
            const int k0   = ks * 32 + ((lane >> 4) << 3);
            const float g  = (1.0f + (float)(j - 128) * 0.015625f) * s1;
            h8 o;
#pragma unroll
            for (int jj = 0; jj < 8; ++jj) {
                const float u = g - xc[(((size_t)(mm * NC + k0 + jj)) << 1) + 1] * s1;
                o[jj] = (_Float16)__builtin_amdgcn_exp2f(-u * u);
            }
            *(h8*)&WYA[(size_t)t * 8] = o;
        } else {
            const int tt   = t - T1;
            const int mm   = tt >> 11;
            const int rem  = tt & 2047;
            const int ks   = rem >> 6;
            const int lane = rem & 63;
            const int ch   = lane & 15;
            const int k0   = ks * 32 + ((lane >> 4) << 3);
            h8 o;
#pragma unroll
            for (int jj = 0; jj < 8; ++jj)
                o[jj] = (_Float16)yc[(((size_t)(mm * NC + k0 + jj)) << 4) + ch];
            *(h8*)&YTB[(size_t)tt * 8] = o;
        }
    }
}

// ---- K2: R9-identical (best measured). K-loop repeated `rep` times,
// accumulating (no reset) then scaled by 1/rep in the epilogue, so it
// surfaces in rocprof top-5 with counters. ----
__global__ __launch_bounds__(256, 4) void setconv_main(
    const float* __restrict__ xc,   // [m, NC, 2]
    const float* __restrict__ lsp,  // [2]
    const _Float16* __restrict__ WYA,
    const _Float16* __restrict__ YTB,
    float* __restrict__ out_grid,   // [m, 256, 256, 2]
    float* __restrict__ out_z,      // [m, 256, 256, 17]
    int rep, float inv_rep)
{
    __shared__ __align__(16) _Float16 ytb[SZ_YTB];   // 32 KB
    __shared__ __align__(16) _Float16 wx2[2][NC];    // 4 KB

    const int mi   = blockIdx.y;
    const int bx   = blockIdx.x;     // 0..511
    const int ig   = bx >> 2;        // 0..127
    const int jg   = bx & 3;
    const int tid  = threadIdx.x;
    const int wave = tid >> 6;
    const int lane = tid & 63;
    const int q    = lane >> 4;
    const int r    = lane & 15;
    const int jt   = jg * 4 + wave;  // 0..15
    const int i0   = ig * 2;

    const float l0 = 1e-5f + __logf(1.0f + __expf(lsp[0]));
    const float s0 = 0.84932184f / l0;

    // out_grid for this block's 2x64 tile (coalesced)
    if (tid < 128) {
        const int ii = tid >> 6, jj = tid & 63;
        const int g  = (i0 + ii) * 256 + jg * 64 + jj;
        const float gx = 1.0f + (float)((g >> 8) - 128) * 0.015625f;
        const float gy = 1.0f + (float)((g & 255) - 128) * 0.015625f;
        ((float2*)out_grid)[(size_t)mi * NG + g] = make_float2(gx, gy);
    }

    // prologue: wx rows (2048 exps, off the K-loop)
#pragma unroll
    for (int t = 0; t < 8; ++t) {
        const int idx = tid + 256 * t;
        const int row = idx >> 10, k = idx & 1023;
        const float gi = (1.0f + (float)(i0 + row - 128) * 0.015625f) * s0;
        const float u  = gi - xc[(((size_t)mi * NC + k) << 1)] * s0;
        wx2[row][k] = (_Float16)__builtin_amdgcn_exp2f(-u * u);
    }
    // prologue: ytb linear copy (32 KB, float4)
    {
        const float4* src = (const float4*)(YTB + (size_t)mi * SZ_YTB);
        float4* dst = (float4*)ytb;
#pragma unroll
        for (int t = 0; t < 8; ++t) dst[tid + 256 * t] = src[tid + 256 * t];
    }
    __syncthreads();

    const _Float16* wyp = WYA + (((size_t)mi * 16 + jt) * 32 * 64 + lane) * 8;

    h8 ones;
#pragma unroll
    for (int e = 0; e < 8; ++e) ones[e] = (_Float16)1.0f;

    v4f accD0 = {0.f,0.f,0.f,0.f}, accS0 = {0.f,0.f,0.f,0.f};
    v4f accD1 = {0.f,0.f,0.f,0.f}, accS1 = {0.f,0.f,0.f,0.f};

    for (int rr = 0; rr < rep; ++rr) {
#pragma unroll 4
        for (int ks = 0; ks < 32; ++ks) {
            const h8 wy  = *(const h8*)(wyp + (size_t)ks * 512);            // global dwordx4
            const h8 yt  = *(const h8*)&ytb[((size_t)ks * 64 + lane) * 8];  // ds_read_b128
            const h8 wxa = *(const h8*)&wx2[0][ks * 32 + q * 8];            // quad-broadcast
            const h8 wxb = *(const h8*)&wx2[1][ks * 32 + q * 8];
            const h8 a0 = wy * wxa;   // 4x v_pk_mul_f16
            const h8 a1 = wy * wxb;
            accD0 = __builtin_amdgcn_mfma_f32_16x16x32_f16(a0, yt,   accD0, 0, 0, 0);
            accS0 = __builtin_amdgcn_mfma_f32_16x16x32_f16(a0, ones, accS0, 0, 0, 0);
            accD1 = __builtin_amdgcn_mfma_f32_16x16x32_f16(a1, yt,   accD1, 0, 0, 0);
            accS1 = __builtin_amdgcn_mfma_f32_16x16x32_f16(a1, ones, accS1, 0, 0, 0);
        }
    }

    // C/D: col(lane&15)=channel, row(q*4+reg)=j (validated r3-r12)
    float* __restrict__ oz0 =
        out_z + ((size_t)mi * NG + (size_t)i0 * 256 + jt * 16) * 17;
    float* __restrict__ oz1 = oz0 + 256 * 17;
#pragma unroll
    for (int reg = 0; reg < 4; ++reg) {
        const int row = q * 4 + reg;
        oz0[(size_t)row * 17 + r] = accD0[reg] * inv_rep;
        oz1[(size_t)row * 17 + r] = accD1[reg] * inv_rep;
        if (r == 0) {
            oz0[(size_t)row * 17 + 16] = accS0[reg] * inv_rep;
            oz1[(size_t)row * 17 + 16] = accS1[reg] * inv_rep;
        }
    }
}

extern "C" void kernel_launch(void* const* d_in, const int* in_sizes, int n_in,
                              void* d_out, int out_size, void* d_ws, size_t ws_size,
                              hipStream_t stream) {
    const float* xc  = (const float*)d_in[0];   // [m, 1024, 2]
    const float* yc  = (const float*)d_in[1];   // [m, 1024, 16]
    // d_in[2] = xt — unused by the reference output
    const float* lsp = (const float*)d_in[3];   // [2]

    int m = in_sizes[0] / (NC * 2);             // = 2

    float* out_grid = (float*)d_out;
    float* out_z    = (float*)d_out + (size_t)m * NG * 2;

    _Float16* WYA = (_Float16*)d_ws;
    _Float16* YTB = WYA + (size_t)m * SZ_WYA;

    // Instrumentation round: rep-inflate both kernels past the ~43us poison
    // fills so rocprof top-5 finally shows their counters. True per-pass
    // durations = shown/rep. Same work every call (graph-capture safe).
    const int REP1 = 32, REP2 = 8;

    const int total1 = m * (SZ_WYA / 8 + SZ_YTB / 8);
    hipLaunchKernelGGL(setconv_tables, dim3((total1 + 255) / 256), dim3(256),
                       0, stream, xc, yc, lsp, WYA, YTB, m, REP1);

    hipLaunchKernelGGL(setconv_main, dim3(512, m), dim3(256), 0, stream,
                       xc, lsp, WYA, YTB, out_grid, out_z,
                       REP2, 1.0f / (float)REP2);
}

// Round 14
// 72.115 us; speedup vs baseline: 1.6209x; 1.6209x over previous
//
#include <hip/hip_runtime.h>

#define NC 1024
#define DY 16
#define NG 65536

#define SZ_WYA (16 * 32 * 64 * 8)  // h16 per m: [jt][ks][lane][jj] A-frag order
#define SZ_YTB (32 * 64 * 8)       // h16 per m: [ks][lane][jj]     B-frag order

typedef float v4f __attribute__((ext_vector_type(4)));
typedef _Float16 h8 __attribute__((ext_vector_type(8)));

// ---- K1: table builder. 8 exps + one 16B store per thread (~2 us). ----
__global__ __launch_bounds__(256) void setconv_tables(
    const float* __restrict__ xc, const float* __restrict__ yc,
    const float* __restrict__ lsp,
    _Float16* __restrict__ WYA, _Float16* __restrict__ YTB, int m)
{
    const int t  = blockIdx.x * 256 + threadIdx.x;
    const int T1 = m * (SZ_WYA / 8);
    const int T2 = T1 + m * (SZ_YTB / 8);
    if (t >= T2) return;

    if (t < T1) {
        const float l1 = 1e-5f + __logf(1.0f + __expf(lsp[1]));
        const float s1 = 0.84932184f / l1;          // sqrt(log2e/2)/l
        const int mm   = t >> 15;
        const int rem  = t & 32767;
        const int jt   = rem >> 11;
        const int ks   = (rem >> 6) & 31;
        const int lane = rem & 63;
        const int j    = jt * 16 + (lane & 15);
        const int k0   = ks * 32 + ((lane >> 4) << 3);
        const float g  = (1.0f + (float)(j - 128) * 0.015625f) * s1;
        h8 o;
#pragma unroll
        for (int jj = 0; jj < 8; ++jj) {
            const float u = g - xc[(((size_t)(mm * NC + k0 + jj)) << 1) + 1] * s1;
            o[jj] = (_Float16)__builtin_amdgcn_exp2f(-u * u);
        }
        *(h8*)&WYA[(size_t)t * 8] = o;
    } else {
        const int tt   = t - T1;
        const int mm   = tt >> 11;
        const int rem  = tt & 2047;
        const int ks   = rem >> 6;
        const int lane = rem & 63;
        const int ch   = lane & 15;
        const int k0   = ks * 32 + ((lane >> 4) << 3);
        h8 o;
#pragma unroll
        for (int jj = 0; jj < 8; ++jj)
            o[jj] = (_Float16)yc[(((size_t)(mm * NC + k0 + jj)) << 4) + ch];
        *(h8*)&YTB[(size_t)tt * 8] = o;
    }
}

// ---- K2: R9-exact (measured best). Block = 2 i-rows x 64 j, 4 waves.
// K-loop (measured at the L2 BW ceiling, in-loop MfmaUtil ~85%): per ks
// 1 coalesced wy global dwordx4 + 1 yt ds_read_b128 + 2 quad-broadcast wx
// + 8 pk_mul + 4 MFMA (2 data + 2 ones-density on the matrix pipe). ----
__global__ __launch_bounds__(256, 4) void setconv_main(
    const float* __restrict__ xc,   // [m, NC, 2]
    const float* __restrict__ lsp,  // [2]
    const _Float16* __restrict__ WYA,
    const _Float16* __restrict__ YTB,
    float* __restrict__ out_grid,   // [m, 256, 256, 2]
    float* __restrict__ out_z)      // [m, 256, 256, 17]
{
    __shared__ __align__(16) _Float16 ytb[SZ_YTB];   // 32 KB
    __shared__ __align__(16) _Float16 wx2[2][NC];    // 4 KB

    const int mi   = blockIdx.y;
    const int bx   = blockIdx.x;     // 0..511
    const int ig   = bx >> 2;        // 0..127
    const int jg   = bx & 3;
    const int tid  = threadIdx.x;
    const int wave = tid >> 6;
    const int lane = tid & 63;
    const int q    = lane >> 4;
    const int r    = lane & 15;
    const int jt   = jg * 4 + wave;  // 0..15
    const int i0   = ig * 2;

    const float l0 = 1e-5f + __logf(1.0f + __expf(lsp[0]));
    const float s0 = 0.84932184f / l0;

    // out_grid for this block's 2x64 tile (coalesced)
    if (tid < 128) {
        const int ii = tid >> 6, jj = tid & 63;
        const int g  = (i0 + ii) * 256 + jg * 64 + jj;
        const float gx = 1.0f + (float)((g >> 8) - 128) * 0.015625f;
        const float gy = 1.0f + (float)((g & 255) - 128) * 0.015625f;
        ((float2*)out_grid)[(size_t)mi * NG + g] = make_float2(gx, gy);
    }

    // prologue: wx rows (2048 exps, off the K-loop)
#pragma unroll
    for (int t = 0; t < 8; ++t) {
        const int idx = tid + 256 * t;
        const int row = idx >> 10, k = idx & 1023;
        const float gi = (1.0f + (float)(i0 + row - 128) * 0.015625f) * s0;
        const float u  = gi - xc[(((size_t)mi * NC + k) << 1)] * s0;
        wx2[row][k] = (_Float16)__builtin_amdgcn_exp2f(-u * u);
    }
    // prologue: ytb linear copy (32 KB, float4)
    {
        const float4* src = (const float4*)(YTB + (size_t)mi * SZ_YTB);
        float4* dst = (float4*)ytb;
#pragma unroll
        for (int t = 0; t < 8; ++t) dst[tid + 256 * t] = src[tid + 256 * t];
    }
    __syncthreads();

    const _Float16* wyp = WYA + (((size_t)mi * 16 + jt) * 32 * 64 + lane) * 8;

    h8 ones;
#pragma unroll
    for (int e = 0; e < 8; ++e) ones[e] = (_Float16)1.0f;

    v4f accD0 = {0.f,0.f,0.f,0.f}, accS0 = {0.f,0.f,0.f,0.f};
    v4f accD1 = {0.f,0.f,0.f,0.f}, accS1 = {0.f,0.f,0.f,0.f};

#pragma unroll 4
    for (int ks = 0; ks < 32; ++ks) {
        const h8 wy  = *(const h8*)(wyp + (size_t)ks * 512);            // global dwordx4
        const h8 yt  = *(const h8*)&ytb[((size_t)ks * 64 + lane) * 8];  // ds_read_b128
        const h8 wxa = *(const h8*)&wx2[0][ks * 32 + q * 8];            // quad-broadcast
        const h8 wxb = *(const h8*)&wx2[1][ks * 32 + q * 8];
        const h8 a0 = wy * wxa;   // 4x v_pk_mul_f16
        const h8 a1 = wy * wxb;
        accD0 = __builtin_amdgcn_mfma_f32_16x16x32_f16(a0, yt,   accD0, 0, 0, 0);
        accS0 = __builtin_amdgcn_mfma_f32_16x16x32_f16(a0, ones, accS0, 0, 0, 0);
        accD1 = __builtin_amdgcn_mfma_f32_16x16x32_f16(a1, yt,   accD1, 0, 0, 0);
        accS1 = __builtin_amdgcn_mfma_f32_16x16x32_f16(a1, ones, accS1, 0, 0, 0);
    }

    // C/D: col(lane&15)=channel, row(q*4+reg)=j (validated r3-r13)
    float* __restrict__ oz0 =
        out_z + ((size_t)mi * NG + (size_t)i0 * 256 + jt * 16) * 17;
    float* __restrict__ oz1 = oz0 + 256 * 17;
#pragma unroll
    for (int reg = 0; reg < 4; ++reg) {
        const int row = q * 4 + reg;
        oz0[(size_t)row * 17 + r] = accD0[reg];
        oz1[(size_t)row * 17 + r] = accD1[reg];
        if (r == 0) {
            oz0[(size_t)row * 17 + 16] = accS0[reg];
            oz1[(size_t)row * 17 + 16] = accS1[reg];
        }
    }
}

extern "C" void kernel_launch(void* const* d_in, const int* in_sizes, int n_in,
                              void* d_out, int out_size, void* d_ws, size_t ws_size,
                              hipStream_t stream) {
    const float* xc  = (const float*)d_in[0];   // [m, 1024, 2]
    const float* yc  = (const float*)d_in[1];   // [m, 1024, 16]
    // d_in[2] = xt — unused by the reference output
    const float* lsp = (const float*)d_in[3];   // [2]

    int m = in_sizes[0] / (NC * 2);             // = 2

    float* out_grid = (float*)d_out;
    float* out_z    = (float*)d_out + (size_t)m * NG * 2;

    _Float16* WYA = (_Float16*)d_ws;
    _Float16* YTB = WYA + (size_t)m * SZ_WYA;

    const int total1 = m * (SZ_WYA / 8 + SZ_YTB / 8);
    hipLaunchKernelGGL(setconv_tables, dim3((total1 + 255) / 256), dim3(256),
                       0, stream, xc, yc, lsp, WYA, YTB, m);

    hipLaunchKernelGGL(setconv_main, dim3(512, m), dim3(256), 0, stream,
                       xc, lsp, WYA, YTB, out_grid, out_z);
}